// Round 2
// baseline (1782.940 us; speedup 1.0000x reference)
//
#include <hip/hip_runtime.h>
#include <hip/hip_fp16.h>

#define DIM 512
#define N_ITERS 10
#define ROWS_PER_WAVE 4
#define PERSIST_BLOCKS 1024
#define PERSIST_THREADS 256

typedef float floatx2 __attribute__((ext_vector_type(2)));

__device__ __forceinline__ unsigned int pack2h(float lo, float hi) {
    __half2 h = __float22half2_rn(make_float2(lo, hi));
    return *reinterpret_cast<unsigned int*>(&h);
}
__device__ __forceinline__ float2 unpack2h(unsigned int u) {
    return __half22float2(*reinterpret_cast<__half2*>(&u));
}
// pack 4 floats -> 4 fp8 e4m3 in one uint
__device__ __forceinline__ unsigned int pack4f8(float f0, float f1, float f2, float f3) {
    int v = 0;
    v = __builtin_amdgcn_cvt_pk_fp8_f32(f0, f1, v, false);
    v = __builtin_amdgcn_cvt_pk_fp8_f32(f2, f3, v, true);
    return (unsigned int)v;
}

// consts[0]=a=exp(alpha), consts[1]=b=exp(beta), consts[2]=1/(4*s*s); bar=0
__global__ void consts_kernel(const float* alpha, const float* beta,
                              const float* sigma, float* consts, int* bar) {
    if (threadIdx.x == 0 && blockIdx.x == 0) {
        float a = expf(alpha[0]);
        float b = expf(beta[0]);
        float s = expf(sigma[0]);
        consts[0] = a;
        consts[1] = b;
        consts[2] = 1.0f / (4.0f * s * s);
        *bar = 0;   // reset software grid barrier (ws is re-poisoned each rep)
    }
}

// one wave per row: x8=fp8(x) [initial state], xn8=fp8(x/||x||), xbh=fp16(x*b)
__global__ void __launch_bounds__(256)
rownorm_kernel(const float* __restrict__ x,
               const float* __restrict__ consts,
               unsigned int* __restrict__ x8,      // uint-per-4, row stride DIM/4
               unsigned int* __restrict__ xn8,
               unsigned short* __restrict__ xbh, int n) {
    int wid = (blockIdx.x * blockDim.x + threadIdx.x) >> 6;
    int lane = threadIdx.x & 63;
    if (wid >= n) return;
    const size_t base = (size_t)wid * DIM + lane * 8;
    const float4* p = (const float4*)(x + base);
    float4 u = p[0];
    float4 v = p[1];
    float s = u.x*u.x + u.y*u.y + u.z*u.z + u.w*u.w
            + v.x*v.x + v.y*v.y + v.z*v.z + v.w*v.w;
    uint2 q;
    q.x = pack4f8(u.x, u.y, u.z, u.w);
    q.y = pack4f8(v.x, v.y, v.z, v.w);
    *(uint2*)(x8 + ((size_t)wid * (DIM / 4) + lane * 2)) = q;
    float b = consts[1];
    uint4 hb;
    hb.x = pack2h(u.x * b, u.y * b); hb.y = pack2h(u.z * b, u.w * b);
    hb.z = pack2h(v.x * b, v.y * b); hb.w = pack2h(v.z * b, v.w * b);
    *(uint4*)(xbh + base) = hb;
    #pragma unroll
    for (int m = 32; m >= 1; m >>= 1) s += __shfl_xor(s, m, 64);
    float inr = rsqrtf(fmaxf(s, 1e-12f));
    uint2 qn;
    qn.x = pack4f8(u.x * inr, u.y * inr, u.z * inr, u.w * inr);
    qn.y = pack4f8(v.x * inr, v.y * inr, v.z * inr, v.w * inr);
    *(uint2*)(xn8 + ((size_t)wid * (DIM / 4) + lane * 2)) = qn;
}

// rstart[r] for r in [0, n]
__global__ void rowptr_kernel(const int* __restrict__ erow, int nnz,
                              int* __restrict__ rstart, int n) {
    int r = blockIdx.x * blockDim.x + threadIdx.x;
    if (r > n) return;
    int lo = 0, hi = nnz;
    while (lo < hi) {
        int mid = (lo + hi) >> 1;
        if (erow[mid] < r) lo = mid + 1; else hi = mid;
    }
    rstart[r] = lo;
}

__device__ __forceinline__ float dot8f8(const float* A, uint2 h) {
    floatx2 p0 = __builtin_amdgcn_cvt_pk_f32_fp8((int)h.x, false);
    floatx2 p1 = __builtin_amdgcn_cvt_pk_f32_fp8((int)h.x, true);
    floatx2 p2 = __builtin_amdgcn_cvt_pk_f32_fp8((int)h.y, false);
    floatx2 p3 = __builtin_amdgcn_cvt_pk_f32_fp8((int)h.y, true);
    return A[0]*p0.x + A[1]*p0.y + A[2]*p1.x + A[3]*p1.y
         + A[4]*p2.x + A[5]*p2.y + A[6]*p3.x + A[7]*p3.y;
}

// one wave per ROW over fp8 normalized rows; 4-deep pipeline; fused inv_denom
__global__ void __launch_bounds__(256)
edge_row_kernel(const unsigned int* __restrict__ xn8,
                const float* __restrict__ eval_,
                const int* __restrict__ ecol,
                const int* __restrict__ rstart,
                const float* __restrict__ consts,
                float* __restrict__ sup, float* __restrict__ inv_denom, int n) {
    int row = (blockIdx.x * blockDim.x + threadIdx.x) >> 6;
    int lane = threadIdx.x & 63;
    if (row >= n) return;
    uint2 hr = *(const uint2*)(xn8 + (size_t)row * (DIM / 4) + lane * 2);
    float A[8];
    {
        floatx2 p0 = __builtin_amdgcn_cvt_pk_f32_fp8((int)hr.x, false);
        floatx2 p1 = __builtin_amdgcn_cvt_pk_f32_fp8((int)hr.x, true);
        floatx2 p2 = __builtin_amdgcn_cvt_pk_f32_fp8((int)hr.y, false);
        floatx2 p3 = __builtin_amdgcn_cvt_pk_f32_fp8((int)hr.y, true);
        A[0]=p0.x; A[1]=p0.y; A[2]=p1.x; A[3]=p1.y;
        A[4]=p2.x; A[5]=p2.y; A[6]=p3.x; A[7]=p3.y;
    }
    float c2 = consts[2];
    int rs = rstart[row], re = rstart[row + 1];
    float norm_acc = 0.0f;
    int e = rs;
    for (; e + 3 < re; e += 4) {
        int c[4]; uint2 h[4]; float s[4];
        #pragma unroll
        for (int j = 0; j < 4; ++j) c[j] = ecol[e + j];
        #pragma unroll
        for (int j = 0; j < 4; ++j)
            h[j] = *(const uint2*)(xn8 + (size_t)c[j] * (DIM / 4) + lane * 2);
        #pragma unroll
        for (int j = 0; j < 4; ++j) s[j] = dot8f8(A, h[j]);
        #pragma unroll
        for (int m = 32; m >= 1; m >>= 1) {
            #pragma unroll
            for (int j = 0; j < 4; ++j) s[j] += __shfl_xor(s[j], m, 64);
        }
        #pragma unroll
        for (int j = 0; j < 4; ++j) {
            float sim = (row == c[j]) ? 0.0f : s[j];
            float sp = eval_[e + j] * expf(sim * c2);
            norm_acc += sp;
            if (lane == 0) sup[e + j] = sp;
        }
    }
    for (; e < re; ++e) {
        int c0 = ecol[e];
        uint2 h0 = *(const uint2*)(xn8 + (size_t)c0 * (DIM / 4) + lane * 2);
        float s0 = dot8f8(A, h0);
        #pragma unroll
        for (int m = 32; m >= 1; m >>= 1) s0 += __shfl_xor(s0, m, 64);
        float sim0 = (row == c0) ? 0.0f : s0;
        float sp0 = eval_[e] * expf(sim0 * c2);
        norm_acc += sp0;
        if (lane == 0) sup[e] = sp0;
    }
    if (lane == 0) {
        float a = consts[0], b = consts[1];
        inv_denom[row] = 1.0f / (b + norm_acc * a + a);
    }
}

#define ACCF8(hh, ww)                                                              \
    do {                                                                           \
        floatx2 p_;                                                                \
        p_ = __builtin_amdgcn_cvt_pk_f32_fp8((int)(hh).x, false); acc0 += (ww)*p_.x; acc1 += (ww)*p_.y; \
        p_ = __builtin_amdgcn_cvt_pk_f32_fp8((int)(hh).x, true);  acc2 += (ww)*p_.x; acc3 += (ww)*p_.y; \
        p_ = __builtin_amdgcn_cvt_pk_f32_fp8((int)(hh).y, false); acc4 += (ww)*p_.x; acc5 += (ww)*p_.y; \
        p_ = __builtin_amdgcn_cvt_pk_f32_fp8((int)(hh).y, true);  acc6 += (ww)*p_.x; acc7 += (ww)*p_.y; \
    } while (0)

// Software grid barrier: monotonic agent-scope counter, no reset races.
// Co-residency is guaranteed: __launch_bounds__(256,4) caps VGPR at 128 ->
// 4 blocks/CU schedulable (LDS=0), grid = 256 CU * 4 = 1024 = exact capacity.
__device__ __forceinline__ void grid_barrier(int* bar, int target) {
    __syncthreads();
    if (threadIdx.x == 0) {
        __threadfence();   // release: agent-scope -> L2 writeback on gfx950
        __hip_atomic_fetch_add(bar, 1, __ATOMIC_RELEASE, __HIP_MEMORY_SCOPE_AGENT);
        while (__hip_atomic_fetch_add(bar, 0, __ATOMIC_RELAXED,
                                      __HIP_MEMORY_SCOPE_AGENT) < target)
            __builtin_amdgcn_s_sleep(2);
        __threadfence();   // acquire: invalidate stale L1/L2 lines
    }
    __syncthreads();
}

// Persistent kernel: all 10 iterations in one launch.
// 4096 waves, each owns ROWS_PER_WAVE=4 rows; lane owns cols 8L..8L+7.
// out kept in fp32 registers; cb = xb*inv_d kept packed fp16 in registers.
// Only the fp8 mirror of out round-trips through memory for the gathers.
__global__ void __launch_bounds__(PERSIST_THREADS, 4)
persist_kernel(const float* __restrict__ x,
               const float* __restrict__ consts,
               const float* __restrict__ inv_denom,
               const int* __restrict__ rstart,
               const float* __restrict__ sup,
               const int* __restrict__ ecol,
               const unsigned short* __restrict__ xbh,
               unsigned int* __restrict__ bufA8,
               unsigned int* __restrict__ bufB8,
               float* __restrict__ out_f32,
               int* __restrict__ bar, int n) {
    int wid = (blockIdx.x * blockDim.x + threadIdx.x) >> 6;
    int lane = threadIdx.x & 63;
    int base_row = wid * ROWS_PER_WAVE;
    const size_t loff16 = lane * 8;
    const size_t loff8 = lane * 2;

    float a = consts[0];
    float o[ROWS_PER_WAVE][8];
    uint4 cbh[ROWS_PER_WAVE];
    float ga[ROWS_PER_WAVE];
    int rs[ROWS_PER_WAVE], re[ROWS_PER_WAVE];

    #pragma unroll
    for (int k = 0; k < ROWS_PER_WAVE; ++k) {
        int row = base_row + k;
        float invd = inv_denom[row];
        ga[k] = a * invd;
        rs[k] = rstart[row];
        re[k] = rstart[row + 1];
        const float4* px = (const float4*)(x + (size_t)row * DIM + loff16);
        float4 u = px[0], v = px[1];
        o[k][0] = u.x; o[k][1] = u.y; o[k][2] = u.z; o[k][3] = u.w;
        o[k][4] = v.x; o[k][5] = v.y; o[k][6] = v.z; o[k][7] = v.w;
        uint4 hb = *(const uint4*)(xbh + (size_t)row * DIM + loff16);
        float2 b0 = unpack2h(hb.x), b1 = unpack2h(hb.y);
        float2 b2 = unpack2h(hb.z), b3 = unpack2h(hb.w);
        uint4 cc;
        cc.x = pack2h(b0.x * invd, b0.y * invd);
        cc.y = pack2h(b1.x * invd, b1.y * invd);
        cc.z = pack2h(b2.x * invd, b2.y * invd);
        cc.w = pack2h(b3.x * invd, b3.y * invd);
        cbh[k] = cc;
    }

    const unsigned int* prev8 = bufA8;
    unsigned int* next8 = bufB8;

    for (int it = 0; it < N_ITERS; ++it) {
        #pragma unroll
        for (int k = 0; k < ROWS_PER_WAVE; ++k) {
            float acc0 = 0.f, acc1 = 0.f, acc2 = 0.f, acc3 = 0.f;
            float acc4 = 0.f, acc5 = 0.f, acc6 = 0.f, acc7 = 0.f;
            int e = rs[k];
            int rend = re[k];
            for (; e + 7 < rend; e += 8) {
                int c[8]; float w[8]; uint2 h[8];
                #pragma unroll
                for (int j = 0; j < 8; ++j) { c[j] = ecol[e + j]; w[j] = sup[e + j]; }
                #pragma unroll
                for (int j = 0; j < 8; ++j)
                    h[j] = *(const uint2*)(prev8 + (size_t)c[j] * (DIM / 4) + loff8);
                #pragma unroll
                for (int j = 0; j < 8; ++j) ACCF8(h[j], w[j]);
            }
            for (; e + 1 < rend; e += 2) {
                int c0 = ecol[e], c1 = ecol[e + 1];
                float w0 = sup[e], w1 = sup[e + 1];
                uint2 h0 = *(const uint2*)(prev8 + (size_t)c0 * (DIM / 4) + loff8);
                uint2 h1 = *(const uint2*)(prev8 + (size_t)c1 * (DIM / 4) + loff8);
                ACCF8(h0, w0);
                ACCF8(h1, w1);
            }
            if (e < rend) {
                float w = sup[e];
                int c = ecol[e];
                uint2 h = *(const uint2*)(prev8 + (size_t)c * (DIM / 4) + loff8);
                ACCF8(h, w);
            }
            float2 c0 = unpack2h(cbh[k].x), c1 = unpack2h(cbh[k].y);
            float2 c2 = unpack2h(cbh[k].z), c3 = unpack2h(cbh[k].w);
            float g = ga[k];
            o[k][0] = c0.x + (acc0 + o[k][0]) * g;
            o[k][1] = c0.y + (acc1 + o[k][1]) * g;
            o[k][2] = c1.x + (acc2 + o[k][2]) * g;
            o[k][3] = c1.y + (acc3 + o[k][3]) * g;
            o[k][4] = c2.x + (acc4 + o[k][4]) * g;
            o[k][5] = c2.y + (acc5 + o[k][5]) * g;
            o[k][6] = c3.x + (acc6 + o[k][6]) * g;
            o[k][7] = c3.y + (acc7 + o[k][7]) * g;
        }
        if (it == N_ITERS - 1) break;
        #pragma unroll
        for (int k = 0; k < ROWS_PER_WAVE; ++k) {
            int row = base_row + k;
            uint2 q;
            q.x = pack4f8(o[k][0], o[k][1], o[k][2], o[k][3]);
            q.y = pack4f8(o[k][4], o[k][5], o[k][6], o[k][7]);
            *(uint2*)(next8 + (size_t)row * (DIM / 4) + loff8) = q;
        }
        grid_barrier(bar, PERSIST_BLOCKS * (it + 1));
        unsigned int* t = (unsigned int*)prev8;
        prev8 = next8;
        next8 = t;
    }

    #pragma unroll
    for (int k = 0; k < ROWS_PER_WAVE; ++k) {
        int row = base_row + k;
        float4* po = (float4*)(out_f32 + (size_t)row * DIM + loff16);
        po[0] = make_float4(o[k][0], o[k][1], o[k][2], o[k][3]);
        po[1] = make_float4(o[k][4], o[k][5], o[k][6], o[k][7]);
    }
}

extern "C" void kernel_launch(void* const* d_in, const int* in_sizes, int n_in,
                              void* d_out, int out_size, void* d_ws, size_t ws_size,
                              hipStream_t stream) {
    const float* x     = (const float*)d_in[0];
    const float* alpha = (const float*)d_in[1];
    const float* beta  = (const float*)d_in[2];
    const float* sigma = (const float*)d_in[3];
    const float* eval_ = (const float*)d_in[4];
    const int* erow = (const int*)d_in[5];
    const int* ecol = (const int*)d_in[6];

    const int n   = in_sizes[0] / DIM;   // 16384
    const int nnz = in_sizes[4];         // 163840

    float* ws        = (float*)d_ws;
    float* consts    = ws;                            // 48 floats
    int*   bar       = (int*)(ws + 48);               // grid barrier counter
    float* inv_denom = ws + 64;                       // n
    int*   rstart    = (int*)(inv_denom + n);         // n+1 (+pad)
    float* sup       = (float*)(rstart + n + 64);     // nnz
    unsigned short* xbh = (unsigned short*)(sup + nnz);          // n*DIM fp16 (16 MB)
    unsigned int*   xn8 = (unsigned int*)(xbh + (size_t)n * DIM); // n*DIM/4 uints (8 MB)
    unsigned int*   bufA8 = xn8 + (size_t)n * (DIM / 4);          // 8 MB
    unsigned int*   bufB8 = bufA8 + (size_t)n * (DIM / 4);        // 8 MB
    float* out_f32 = (float*)d_out;

    consts_kernel<<<1, 64, 0, stream>>>(alpha, beta, sigma, consts, bar);
    rownorm_kernel<<<(n * 64) / 256, 256, 0, stream>>>(x, consts, bufA8, xn8, xbh, n);
    rowptr_kernel<<<(n + 256) / 256, 256, 0, stream>>>(erow, nnz, rstart, n);
    edge_row_kernel<<<(n * 64) / 256, 256, 0, stream>>>(xn8, eval_, ecol,
                                                        rstart, consts,
                                                        sup, inv_denom, n);
    persist_kernel<<<PERSIST_BLOCKS, PERSIST_THREADS, 0, stream>>>(
        x, consts, inv_denom, rstart, sup, ecol, xbh,
        bufA8, bufB8, out_f32, bar, n);
}

// Round 4
// 344.192 us; speedup vs baseline: 5.1801x; 5.1801x over previous
//
#include <hip/hip_runtime.h>
#include <hip/hip_fp16.h>

#define DIM 512
#define N_ITERS 10

typedef float floatx2 __attribute__((ext_vector_type(2)));
typedef float fx4 __attribute__((ext_vector_type(4)));
typedef unsigned int ux4 __attribute__((ext_vector_type(4)));

__device__ __forceinline__ unsigned int pack2h(float lo, float hi) {
    __half2 h = __float22half2_rn(make_float2(lo, hi));
    return *reinterpret_cast<unsigned int*>(&h);
}
__device__ __forceinline__ float2 unpack2h(unsigned int u) {
    return __half22float2(*reinterpret_cast<__half2*>(&u));
}
// pack 4 floats -> 4 fp8 e4m3 in one uint
__device__ __forceinline__ unsigned int pack4f8(float f0, float f1, float f2, float f3) {
    int v = 0;
    v = __builtin_amdgcn_cvt_pk_fp8_f32(f0, f1, v, false);
    v = __builtin_amdgcn_cvt_pk_fp8_f32(f2, f3, v, true);
    return (unsigned int)v;
}

// consts[0]=a=exp(alpha), consts[1]=b=exp(beta), consts[2]=1/(4*s*s)
__global__ void consts_kernel(const float* alpha, const float* beta,
                              const float* sigma, float* consts) {
    if (threadIdx.x == 0 && blockIdx.x == 0) {
        float a = expf(alpha[0]);
        float b = expf(beta[0]);
        float s = expf(sigma[0]);
        consts[0] = a;
        consts[1] = b;
        consts[2] = 1.0f / (4.0f * s * s);
    }
}

// one wave per row. Writes:
//   xc8: interleaved fp8, row stride 256 uints; per lane uint4
//        {fp8(xn)[0:4], fp8(xn)[4:8], fp8(x)[0:4], fp8(x)[4:8]}
//   xbh: fp16(x*b), row stride DIM
__global__ void __launch_bounds__(256)
rownorm_kernel(const float* __restrict__ x,
               const float* __restrict__ consts,
               unsigned int* __restrict__ xc8,
               unsigned short* __restrict__ xbh, int n) {
    int wid = (blockIdx.x * blockDim.x + threadIdx.x) >> 6;
    int lane = threadIdx.x & 63;
    if (wid >= n) return;
    const size_t base = (size_t)wid * DIM + lane * 8;
    const fx4* p = (const fx4*)(x + base);
    fx4 u = __builtin_nontemporal_load(p);
    fx4 v = __builtin_nontemporal_load(p + 1);
    float s = u.x*u.x + u.y*u.y + u.z*u.z + u.w*u.w
            + v.x*v.x + v.y*v.y + v.z*v.z + v.w*v.w;
    float b = consts[1];
    ux4 hb;
    hb.x = pack2h(u.x * b, u.y * b); hb.y = pack2h(u.z * b, u.w * b);
    hb.z = pack2h(v.x * b, v.y * b); hb.w = pack2h(v.z * b, v.w * b);
    *(ux4*)(xbh + base) = hb;
    #pragma unroll
    for (int m = 32; m >= 1; m >>= 1) s += __shfl_xor(s, m, 64);
    float inr = rsqrtf(fmaxf(s, 1e-12f));
    ux4 q;
    q.x = pack4f8(u.x * inr, u.y * inr, u.z * inr, u.w * inr);
    q.y = pack4f8(v.x * inr, v.y * inr, v.z * inr, v.w * inr);
    q.z = pack4f8(u.x, u.y, u.z, u.w);
    q.w = pack4f8(v.x, v.y, v.z, v.w);
    *(ux4*)(xc8 + ((size_t)wid * 256 + lane * 4)) = q;
}

// rstart[r] for r in [0, n]
__global__ void rowptr_kernel(const int* __restrict__ erow, int nnz,
                              int* __restrict__ rstart, int n) {
    int r = blockIdx.x * blockDim.x + threadIdx.x;
    if (r > n) return;
    int lo = 0, hi = nnz;
    while (lo < hi) {
        int mid = (lo + hi) >> 1;
        if (erow[mid] < r) lo = mid + 1; else hi = mid;
    }
    rstart[r] = lo;
}

__device__ __forceinline__ float dot8f8(const float* A, unsigned int lo, unsigned int hi) {
    floatx2 p0 = __builtin_amdgcn_cvt_pk_f32_fp8((int)lo, false);
    floatx2 p1 = __builtin_amdgcn_cvt_pk_f32_fp8((int)lo, true);
    floatx2 p2 = __builtin_amdgcn_cvt_pk_f32_fp8((int)hi, false);
    floatx2 p3 = __builtin_amdgcn_cvt_pk_f32_fp8((int)hi, true);
    return A[0]*p0.x + A[1]*p0.y + A[2]*p1.x + A[3]*p1.y
         + A[4]*p2.x + A[5]*p2.y + A[6]*p3.x + A[7]*p3.y;
}

// packed accumulate: acc0..3 are floatx2 -> v_pk_fma_f32
#define ACCP(lo, hi, w2)                                                          \
    do {                                                                          \
        acc0 += (w2) * __builtin_amdgcn_cvt_pk_f32_fp8((int)(lo), false);         \
        acc1 += (w2) * __builtin_amdgcn_cvt_pk_f32_fp8((int)(lo), true);          \
        acc2 += (w2) * __builtin_amdgcn_cvt_pk_f32_fp8((int)(hi), false);         \
        acc3 += (w2) * __builtin_amdgcn_cvt_pk_f32_fp8((int)(hi), true);          \
    } while (0)

// Fused edge_row + iteration 1. One wave per row.
// Per edge: one dwordx4 gather from xc8 gives BOTH the normalized row
// (for the cosine-sim dot) and the raw fp8 row (for the axpy).
// Everything is row-local: sup, inv_denom, and out1 all computed here.
__global__ void __launch_bounds__(256)
fused1_kernel(const unsigned int* __restrict__ xc8,
              const float* __restrict__ x,
              const float* __restrict__ eval_,
              const int* __restrict__ ecol,
              const int* __restrict__ rstart,
              const float* __restrict__ consts,
              float* __restrict__ sup, float* __restrict__ inv_denom,
              unsigned short* __restrict__ next16,
              unsigned int* __restrict__ next8, int n) {
    int row = (blockIdx.x * blockDim.x + threadIdx.x) >> 6;
    int lane = threadIdx.x & 63;
    if (row >= n) return;
    ux4 hr = *(const ux4*)(xc8 + (size_t)row * 256 + lane * 4);
    float A[8];
    {
        floatx2 p0 = __builtin_amdgcn_cvt_pk_f32_fp8((int)hr.x, false);
        floatx2 p1 = __builtin_amdgcn_cvt_pk_f32_fp8((int)hr.x, true);
        floatx2 p2 = __builtin_amdgcn_cvt_pk_f32_fp8((int)hr.y, false);
        floatx2 p3 = __builtin_amdgcn_cvt_pk_f32_fp8((int)hr.y, true);
        A[0]=p0.x; A[1]=p0.y; A[2]=p1.x; A[3]=p1.y;
        A[4]=p2.x; A[5]=p2.y; A[6]=p3.x; A[7]=p3.y;
    }
    float a = consts[0], b = consts[1], c2 = consts[2];
    int rs = rstart[row], re = rstart[row + 1];
    float norm_acc = 0.0f;
    floatx2 acc0 = {0.f, 0.f}, acc1 = {0.f, 0.f}, acc2 = {0.f, 0.f}, acc3 = {0.f, 0.f};
    int e = rs;
    for (; e + 3 < re; e += 4) {
        int c[4]; float ev[4]; ux4 h[4]; float s[4];
        #pragma unroll
        for (int j = 0; j < 4; ++j) { c[j] = ecol[e + j]; ev[j] = eval_[e + j]; }
        #pragma unroll
        for (int j = 0; j < 4; ++j)
            h[j] = *(const ux4*)(xc8 + (size_t)c[j] * 256 + lane * 4);
        #pragma unroll
        for (int j = 0; j < 4; ++j) s[j] = dot8f8(A, h[j].x, h[j].y);
        #pragma unroll
        for (int m = 32; m >= 1; m >>= 1) {
            #pragma unroll
            for (int j = 0; j < 4; ++j) s[j] += __shfl_xor(s[j], m, 64);
        }
        #pragma unroll
        for (int j = 0; j < 4; ++j) {
            float sim = (row == c[j]) ? 0.0f : s[j];
            float sp = ev[j] * expf(sim * c2);
            norm_acc += sp;
            if (lane == 0) sup[e + j] = sp;
            floatx2 w2 = {sp, sp};
            ACCP(h[j].z, h[j].w, w2);
        }
    }
    for (; e < re; ++e) {
        int c0 = ecol[e];
        float ev0 = eval_[e];
        ux4 h0 = *(const ux4*)(xc8 + (size_t)c0 * 256 + lane * 4);
        float s0 = dot8f8(A, h0.x, h0.y);
        #pragma unroll
        for (int m = 32; m >= 1; m >>= 1) s0 += __shfl_xor(s0, m, 64);
        float sim0 = (row == c0) ? 0.0f : s0;
        float sp0 = ev0 * expf(sim0 * c2);
        norm_acc += sp0;
        if (lane == 0) sup[e] = sp0;
        floatx2 w2 = {sp0, sp0};
        ACCP(h0.z, h0.w, w2);
    }
    float inv_d = 1.0f / (b + norm_acc * a + a);
    if (lane == 0) inv_denom[row] = inv_d;
    // epilogue: out1 = (x*b + (Ax0 + x)*a) * inv_d, self-term in f32
    const size_t base = (size_t)row * DIM + lane * 8;
    const fx4* px = (const fx4*)(x + base);
    fx4 u = __builtin_nontemporal_load(px);
    fx4 v = __builtin_nontemporal_load(px + 1);
    float r0 = (u.x * b + (acc0.x + u.x) * a) * inv_d;
    float r1 = (u.y * b + (acc0.y + u.y) * a) * inv_d;
    float r2 = (u.z * b + (acc1.x + u.z) * a) * inv_d;
    float r3 = (u.w * b + (acc1.y + u.w) * a) * inv_d;
    float r4 = (v.x * b + (acc2.x + v.x) * a) * inv_d;
    float r5 = (v.y * b + (acc2.y + v.y) * a) * inv_d;
    float r6 = (v.z * b + (acc3.x + v.z) * a) * inv_d;
    float r7 = (v.w * b + (acc3.y + v.w) * a) * inv_d;
    ux4 ho;
    ho.x = pack2h(r0, r1); ho.y = pack2h(r2, r3);
    ho.z = pack2h(r4, r5); ho.w = pack2h(r6, r7);
    __builtin_nontemporal_store(ho, (ux4*)(next16 + base));
    uint2 q;
    q.x = pack4f8(r0, r1, r2, r3);
    q.y = pack4f8(r4, r5, r6, r7);
    *(uint2*)(next8 + (size_t)row * (DIM / 4) + lane * 2) = q;
}

// one wave per row; lane owns cols 8L..8L+7; gathers fp8, self/epilogue fp16.
// Streaming fp16 traffic (prev16/xbh/next16) is non-temporal so the fp8
// gather buffer stays L2-resident.
__global__ void __launch_bounds__(256)
iter_kernel(const unsigned short* __restrict__ prev16,
            const unsigned int* __restrict__ prev8,
            unsigned short* __restrict__ next16,
            unsigned int* __restrict__ next8,
            float* __restrict__ out_f32, int last,
            const float* __restrict__ consts, const float* __restrict__ inv_denom,
            const float* __restrict__ sup, const int* __restrict__ ecol,
            const int* __restrict__ rstart,
            const unsigned short* __restrict__ xbh, int n) {
    int row = (blockIdx.x * blockDim.x + threadIdx.x) >> 6;
    int lane = threadIdx.x & 63;
    if (row >= n) return;
    float a = consts[0];
    float inv_d = inv_denom[row];
    int rs = rstart[row], re = rstart[row + 1];
    const size_t loff16 = lane * 8;
    const size_t base16 = (size_t)row * DIM + loff16;
    const size_t loff8 = lane * 2;
    floatx2 acc0 = {0.f, 0.f}, acc1 = {0.f, 0.f}, acc2 = {0.f, 0.f}, acc3 = {0.f, 0.f};
    int e = rs;
    for (; e + 7 < re; e += 8) {
        int c[8]; float w[8]; uint2 h[8];
        #pragma unroll
        for (int j = 0; j < 8; ++j) { c[j] = ecol[e + j]; w[j] = sup[e + j]; }
        #pragma unroll
        for (int j = 0; j < 8; ++j)
            h[j] = *(const uint2*)(prev8 + (size_t)c[j] * (DIM / 4) + loff8);
        #pragma unroll
        for (int j = 0; j < 8; ++j) {
            floatx2 w2 = {w[j], w[j]};
            ACCP(h[j].x, h[j].y, w2);
        }
    }
    for (; e + 1 < re; e += 2) {
        int c0 = ecol[e], c1 = ecol[e + 1];
        float w0 = sup[e], w1 = sup[e + 1];
        uint2 h0 = *(const uint2*)(prev8 + (size_t)c0 * (DIM / 4) + loff8);
        uint2 h1 = *(const uint2*)(prev8 + (size_t)c1 * (DIM / 4) + loff8);
        floatx2 w20 = {w0, w0}; ACCP(h0.x, h0.y, w20);
        floatx2 w21 = {w1, w1}; ACCP(h1.x, h1.y, w21);
    }
    if (e < re) {
        float w = sup[e];
        int c = ecol[e];
        uint2 h = *(const uint2*)(prev8 + (size_t)c * (DIM / 4) + loff8);
        floatx2 w2 = {w, w}; ACCP(h.x, h.y, w2);
    }
    ux4 hs = __builtin_nontemporal_load((const ux4*)(prev16 + base16));
    ux4 hx = __builtin_nontemporal_load((const ux4*)(xbh + base16));
    float2 s0 = unpack2h(hs.x), s1 = unpack2h(hs.y);
    float2 s2 = unpack2h(hs.z), s3 = unpack2h(hs.w);
    float2 x0 = unpack2h(hx.x), x1 = unpack2h(hx.y);
    float2 x2 = unpack2h(hx.z), x3 = unpack2h(hx.w);
    float r0 = (x0.x + (acc0.x + s0.x) * a) * inv_d;
    float r1 = (x0.y + (acc0.y + s0.y) * a) * inv_d;
    float r2 = (x1.x + (acc1.x + s1.x) * a) * inv_d;
    float r3 = (x1.y + (acc1.y + s1.y) * a) * inv_d;
    float r4 = (x2.x + (acc2.x + s2.x) * a) * inv_d;
    float r5 = (x2.y + (acc2.y + s2.y) * a) * inv_d;
    float r6 = (x3.x + (acc3.x + s3.x) * a) * inv_d;
    float r7 = (x3.y + (acc3.y + s3.y) * a) * inv_d;
    if (last) {
        fx4* o = (fx4*)(out_f32 + base16);
        fx4 o0 = {r0, r1, r2, r3};
        fx4 o1 = {r4, r5, r6, r7};
        __builtin_nontemporal_store(o0, o);
        __builtin_nontemporal_store(o1, o + 1);
    } else {
        ux4 ho;
        ho.x = pack2h(r0, r1); ho.y = pack2h(r2, r3);
        ho.z = pack2h(r4, r5); ho.w = pack2h(r6, r7);
        __builtin_nontemporal_store(ho, (ux4*)(next16 + base16));
        uint2 q;
        q.x = pack4f8(r0, r1, r2, r3);
        q.y = pack4f8(r4, r5, r6, r7);
        *(uint2*)(next8 + (size_t)row * (DIM / 4) + loff8) = q;
    }
}

extern "C" void kernel_launch(void* const* d_in, const int* in_sizes, int n_in,
                              void* d_out, int out_size, void* d_ws, size_t ws_size,
                              hipStream_t stream) {
    const float* x     = (const float*)d_in[0];
    const float* alpha = (const float*)d_in[1];
    const float* beta  = (const float*)d_in[2];
    const float* sigma = (const float*)d_in[3];
    const float* eval_ = (const float*)d_in[4];
    const int* erow = (const int*)d_in[5];
    const int* ecol = (const int*)d_in[6];

    const int n   = in_sizes[0] / DIM;   // 16384
    const int nnz = in_sizes[4];         // 163840

    float* ws        = (float*)d_ws;
    float* consts    = ws;                            // 64 floats
    float* inv_denom = ws + 64;                       // n
    int*   rstart    = (int*)(inv_denom + n);         // n+1 (+pad)
    float* sup       = (float*)(rstart + n + 64);     // nnz
    unsigned short* xbh    = (unsigned short*)(sup + nnz);           // n*DIM fp16 (16 MB)
    unsigned short* bufB16 = xbh + (size_t)n * DIM;                  // n*DIM fp16 (16 MB)
    unsigned int*   xc8    = (unsigned int*)(bufB16 + (size_t)n * DIM); // n*256 uints (16 MB)
    unsigned int*   bufB8  = xc8 + (size_t)n * 256;                  // 8 MB
    unsigned int*   bufA8  = xc8;   // alias: xc8 is dead after fused1_kernel,
                                    // bufA8 first written by the k=0 iter launch
    unsigned short* bufA16 = (unsigned short*)d_out;                 // first 16 MB of d_out
    float* out_f32 = (float*)d_out;

    consts_kernel<<<1, 64, 0, stream>>>(alpha, beta, sigma, consts);
    rownorm_kernel<<<(n * 64) / 256, 256, 0, stream>>>(x, consts, xc8, xbh, n);
    rowptr_kernel<<<(n + 256) / 256, 256, 0, stream>>>(erow, nnz, rstart, n);
    // fused cosine-sim + sup + inv_denom + iteration 1 (writes B buffers)
    fused1_kernel<<<(n * 64) / 256, 256, 0, stream>>>(xc8, x, eval_, ecol, rstart,
                                                      consts, sup, inv_denom,
                                                      bufB16, bufB8, n);
    // iterations 2..10: k even reads B writes A; k odd reads A writes B;
    // k=8 (iteration 10) reads B and writes fp32 d_out.
    for (int k = 0; k < N_ITERS - 1; ++k) {
        const unsigned short* prev16 = (k & 1) ? bufA16 : bufB16;
        const unsigned int*   prev8  = (k & 1) ? bufA8  : bufB8;
        unsigned short* next16 = (k & 1) ? bufB16 : bufA16;
        unsigned int*   next8  = (k & 1) ? bufB8  : bufA8;
        int last = (k == N_ITERS - 2) ? 1 : 0;
        iter_kernel<<<(n * 64) / 256, 256, 0, stream>>>(prev16, prev8, next16, next8,
                                                        out_f32, last,
                                                        consts, inv_denom, sup, ecol,
                                                        rstart, xbh, n);
    }
}

// Round 5
// 332.323 us; speedup vs baseline: 5.3651x; 1.0357x over previous
//
#include <hip/hip_runtime.h>
#include <hip/hip_fp16.h>

#define DIM 512
#define N_ITERS 10

typedef float floatx2 __attribute__((ext_vector_type(2)));
typedef float fx4 __attribute__((ext_vector_type(4)));
typedef unsigned int ux4 __attribute__((ext_vector_type(4)));

__device__ __forceinline__ unsigned int pack2h(float lo, float hi) {
    __half2 h = __float22half2_rn(make_float2(lo, hi));
    return *reinterpret_cast<unsigned int*>(&h);
}
__device__ __forceinline__ float2 unpack2h(unsigned int u) {
    return __half22float2(*reinterpret_cast<__half2*>(&u));
}
// pack 4 floats -> 4 fp8 e4m3 in one uint
__device__ __forceinline__ unsigned int pack4f8(float f0, float f1, float f2, float f3) {
    int v = 0;
    v = __builtin_amdgcn_cvt_pk_fp8_f32(f0, f1, v, false);
    v = __builtin_amdgcn_cvt_pk_fp8_f32(f2, f3, v, true);
    return (unsigned int)v;
}

// Merged consts + rowptr + rownorm (saves 2 launches).
// Every thread computes b locally (no intra-kernel dependency on consts[]).
// Writes:
//   consts[0]=a, consts[1]=b, consts[2]=1/(4*s*s)           (thread 0)
//   rstart[r] for r in [0,n]                                 (threads 0..n)
//   xc8: interleaved fp8, row stride 256 uints; per lane uint4
//        {fp8(xn)[0:4], fp8(xn)[4:8], fp8(x)[0:4], fp8(x)[4:8]}
//   xbh: fp16(x*b), row stride DIM
__global__ void __launch_bounds__(256)
prep_kernel(const float* __restrict__ x,
            const float* __restrict__ alpha,
            const float* __restrict__ beta,
            const float* __restrict__ sigma,
            const int* __restrict__ erow, int nnz,
            float* __restrict__ consts,
            int* __restrict__ rstart,
            unsigned int* __restrict__ xc8,
            unsigned short* __restrict__ xbh, int n) {
    int tid = blockIdx.x * blockDim.x + threadIdx.x;
    float b = expf(beta[0]);
    if (tid == 0) {
        float a = expf(alpha[0]);
        float s = expf(sigma[0]);
        consts[0] = a;
        consts[1] = b;
        consts[2] = 1.0f / (4.0f * s * s);
    }
    if (tid <= n) {
        int lo = 0, hi = nnz;
        while (lo < hi) {
            int mid = (lo + hi) >> 1;
            if (erow[mid] < tid) lo = mid + 1; else hi = mid;
        }
        rstart[tid] = lo;
    }
    int wid = tid >> 6;
    int lane = tid & 63;
    if (wid >= n) return;
    const size_t base = (size_t)wid * DIM + lane * 8;
    const fx4* p = (const fx4*)(x + base);
    fx4 u = p[0];
    fx4 v = p[1];
    float s = u.x*u.x + u.y*u.y + u.z*u.z + u.w*u.w
            + v.x*v.x + v.y*v.y + v.z*v.z + v.w*v.w;
    ux4 hb;
    hb.x = pack2h(u.x * b, u.y * b); hb.y = pack2h(u.z * b, u.w * b);
    hb.z = pack2h(v.x * b, v.y * b); hb.w = pack2h(v.z * b, v.w * b);
    *(ux4*)(xbh + base) = hb;
    #pragma unroll
    for (int m = 32; m >= 1; m >>= 1) s += __shfl_xor(s, m, 64);
    float inr = rsqrtf(fmaxf(s, 1e-12f));
    ux4 q;
    q.x = pack4f8(u.x * inr, u.y * inr, u.z * inr, u.w * inr);
    q.y = pack4f8(v.x * inr, v.y * inr, v.z * inr, v.w * inr);
    q.z = pack4f8(u.x, u.y, u.z, u.w);
    q.w = pack4f8(v.x, v.y, v.z, v.w);
    *(ux4*)(xc8 + ((size_t)wid * 256 + lane * 4)) = q;
}

__device__ __forceinline__ float dot8f8(const float* A, unsigned int lo, unsigned int hi) {
    floatx2 p0 = __builtin_amdgcn_cvt_pk_f32_fp8((int)lo, false);
    floatx2 p1 = __builtin_amdgcn_cvt_pk_f32_fp8((int)lo, true);
    floatx2 p2 = __builtin_amdgcn_cvt_pk_f32_fp8((int)hi, false);
    floatx2 p3 = __builtin_amdgcn_cvt_pk_f32_fp8((int)hi, true);
    return A[0]*p0.x + A[1]*p0.y + A[2]*p1.x + A[3]*p1.y
         + A[4]*p2.x + A[5]*p2.y + A[6]*p3.x + A[7]*p3.y;
}

// packed accumulate: acc0..3 are floatx2 -> v_pk_fma_f32
#define ACCP(lo, hi, w2)                                                          \
    do {                                                                          \
        acc0 += (w2) * __builtin_amdgcn_cvt_pk_f32_fp8((int)(lo), false);         \
        acc1 += (w2) * __builtin_amdgcn_cvt_pk_f32_fp8((int)(lo), true);          \
        acc2 += (w2) * __builtin_amdgcn_cvt_pk_f32_fp8((int)(hi), false);         \
        acc3 += (w2) * __builtin_amdgcn_cvt_pk_f32_fp8((int)(hi), true);          \
    } while (0)

// Fused edge_row + iteration 1. One wave per row.
// Per edge: one dwordx4 gather from xc8 gives BOTH the normalized row
// (for the cosine-sim dot) and the raw fp8 row (for the axpy).
// x epilogue loads hoisted above the edge loop (issue-early).
__global__ void __launch_bounds__(256)
fused1_kernel(const unsigned int* __restrict__ xc8,
              const float* __restrict__ x,
              const float* __restrict__ eval_,
              const int* __restrict__ ecol,
              const int* __restrict__ rstart,
              const float* __restrict__ consts,
              float* __restrict__ sup, float* __restrict__ inv_denom,
              unsigned short* __restrict__ next16,
              unsigned int* __restrict__ next8, int n) {
    int row = (blockIdx.x * blockDim.x + threadIdx.x) >> 6;
    int lane = threadIdx.x & 63;
    if (row >= n) return;
    const size_t base = (size_t)row * DIM + lane * 8;
    // issue-early: self row (fp8 packed) + epilogue x loads
    ux4 hr = *(const ux4*)(xc8 + (size_t)row * 256 + lane * 4);
    const fx4* px = (const fx4*)(x + base);
    fx4 u = px[0];
    fx4 v = px[1];
    float A[8];
    {
        floatx2 p0 = __builtin_amdgcn_cvt_pk_f32_fp8((int)hr.x, false);
        floatx2 p1 = __builtin_amdgcn_cvt_pk_f32_fp8((int)hr.x, true);
        floatx2 p2 = __builtin_amdgcn_cvt_pk_f32_fp8((int)hr.y, false);
        floatx2 p3 = __builtin_amdgcn_cvt_pk_f32_fp8((int)hr.y, true);
        A[0]=p0.x; A[1]=p0.y; A[2]=p1.x; A[3]=p1.y;
        A[4]=p2.x; A[5]=p2.y; A[6]=p3.x; A[7]=p3.y;
    }
    float a = consts[0], b = consts[1], c2 = consts[2];
    int rs = rstart[row], re = rstart[row + 1];
    float norm_acc = 0.0f;
    floatx2 acc0 = {0.f, 0.f}, acc1 = {0.f, 0.f}, acc2 = {0.f, 0.f}, acc3 = {0.f, 0.f};
    int e = rs;
    for (; e + 3 < re; e += 4) {
        int c[4]; float ev[4]; ux4 h[4]; float s[4];
        #pragma unroll
        for (int j = 0; j < 4; ++j) { c[j] = ecol[e + j]; ev[j] = eval_[e + j]; }
        #pragma unroll
        for (int j = 0; j < 4; ++j)
            h[j] = *(const ux4*)(xc8 + (size_t)c[j] * 256 + lane * 4);
        #pragma unroll
        for (int j = 0; j < 4; ++j) s[j] = dot8f8(A, h[j].x, h[j].y);
        #pragma unroll
        for (int m = 32; m >= 1; m >>= 1) {
            #pragma unroll
            for (int j = 0; j < 4; ++j) s[j] += __shfl_xor(s[j], m, 64);
        }
        #pragma unroll
        for (int j = 0; j < 4; ++j) {
            float sim = (row == c[j]) ? 0.0f : s[j];
            float sp = ev[j] * expf(sim * c2);
            norm_acc += sp;
            if (lane == 0) sup[e + j] = sp;
            floatx2 w2 = {sp, sp};
            ACCP(h[j].z, h[j].w, w2);
        }
    }
    for (; e < re; ++e) {
        int c0 = ecol[e];
        float ev0 = eval_[e];
        ux4 h0 = *(const ux4*)(xc8 + (size_t)c0 * 256 + lane * 4);
        float s0 = dot8f8(A, h0.x, h0.y);
        #pragma unroll
        for (int m = 32; m >= 1; m >>= 1) s0 += __shfl_xor(s0, m, 64);
        float sim0 = (row == c0) ? 0.0f : s0;
        float sp0 = ev0 * expf(sim0 * c2);
        norm_acc += sp0;
        if (lane == 0) sup[e] = sp0;
        floatx2 w2 = {sp0, sp0};
        ACCP(h0.z, h0.w, w2);
    }
    float inv_d = 1.0f / (b + norm_acc * a + a);
    if (lane == 0) inv_denom[row] = inv_d;
    // epilogue: out1 = (x*b + (Ax0 + x)*a) * inv_d, self-term in f32
    float r0 = (u.x * b + (acc0.x + u.x) * a) * inv_d;
    float r1 = (u.y * b + (acc0.y + u.y) * a) * inv_d;
    float r2 = (u.z * b + (acc1.x + u.z) * a) * inv_d;
    float r3 = (u.w * b + (acc1.y + u.w) * a) * inv_d;
    float r4 = (v.x * b + (acc2.x + v.x) * a) * inv_d;
    float r5 = (v.y * b + (acc2.y + v.y) * a) * inv_d;
    float r6 = (v.z * b + (acc3.x + v.z) * a) * inv_d;
    float r7 = (v.w * b + (acc3.y + v.w) * a) * inv_d;
    ux4 ho;
    ho.x = pack2h(r0, r1); ho.y = pack2h(r2, r3);
    ho.z = pack2h(r4, r5); ho.w = pack2h(r6, r7);
    *(ux4*)(next16 + base) = ho;
    uint2 q;
    q.x = pack4f8(r0, r1, r2, r3);
    q.y = pack4f8(r4, r5, r6, r7);
    *(uint2*)(next8 + (size_t)row * (DIM / 4) + lane * 2) = q;
}

// one wave per row; lane owns cols 8L..8L+7; gathers fp8, self/epilogue fp16.
// Self-state + xbh loads hoisted above the gather loop (issue-early: their
// ~500-cycle latency hides under the edge gathers).
__global__ void __launch_bounds__(256)
iter_kernel(const unsigned short* __restrict__ prev16,
            const unsigned int* __restrict__ prev8,
            unsigned short* __restrict__ next16,
            unsigned int* __restrict__ next8,
            float* __restrict__ out_f32, int last,
            const float* __restrict__ consts, const float* __restrict__ inv_denom,
            const float* __restrict__ sup, const int* __restrict__ ecol,
            const int* __restrict__ rstart,
            const unsigned short* __restrict__ xbh, int n) {
    int row = (blockIdx.x * blockDim.x + threadIdx.x) >> 6;
    int lane = threadIdx.x & 63;
    if (row >= n) return;
    const size_t loff16 = lane * 8;
    const size_t base16 = (size_t)row * DIM + loff16;
    const size_t loff8 = lane * 2;
    // issue-early epilogue streams
    ux4 hs = *(const ux4*)(prev16 + base16);
    ux4 hx = *(const ux4*)(xbh + base16);
    float a = consts[0];
    float inv_d = inv_denom[row];
    int rs = rstart[row], re = rstart[row + 1];
    floatx2 acc0 = {0.f, 0.f}, acc1 = {0.f, 0.f}, acc2 = {0.f, 0.f}, acc3 = {0.f, 0.f};
    int e = rs;
    for (; e + 7 < re; e += 8) {
        int c[8]; float w[8]; uint2 h[8];
        #pragma unroll
        for (int j = 0; j < 8; ++j) { c[j] = ecol[e + j]; w[j] = sup[e + j]; }
        #pragma unroll
        for (int j = 0; j < 8; ++j)
            h[j] = *(const uint2*)(prev8 + (size_t)c[j] * (DIM / 4) + loff8);
        #pragma unroll
        for (int j = 0; j < 8; ++j) {
            floatx2 w2 = {w[j], w[j]};
            ACCP(h[j].x, h[j].y, w2);
        }
    }
    for (; e + 1 < re; e += 2) {
        int c0 = ecol[e], c1 = ecol[e + 1];
        float w0 = sup[e], w1 = sup[e + 1];
        uint2 h0 = *(const uint2*)(prev8 + (size_t)c0 * (DIM / 4) + loff8);
        uint2 h1 = *(const uint2*)(prev8 + (size_t)c1 * (DIM / 4) + loff8);
        floatx2 w20 = {w0, w0}; ACCP(h0.x, h0.y, w20);
        floatx2 w21 = {w1, w1}; ACCP(h1.x, h1.y, w21);
    }
    if (e < re) {
        float w = sup[e];
        int c = ecol[e];
        uint2 h = *(const uint2*)(prev8 + (size_t)c * (DIM / 4) + loff8);
        floatx2 w2 = {w, w}; ACCP(h.x, h.y, w2);
    }
    float2 s0 = unpack2h(hs.x), s1 = unpack2h(hs.y);
    float2 s2 = unpack2h(hs.z), s3 = unpack2h(hs.w);
    float2 x0 = unpack2h(hx.x), x1 = unpack2h(hx.y);
    float2 x2 = unpack2h(hx.z), x3 = unpack2h(hx.w);
    float r0 = (x0.x + (acc0.x + s0.x) * a) * inv_d;
    float r1 = (x0.y + (acc0.y + s0.y) * a) * inv_d;
    float r2 = (x1.x + (acc1.x + s1.x) * a) * inv_d;
    float r3 = (x1.y + (acc1.y + s1.y) * a) * inv_d;
    float r4 = (x2.x + (acc2.x + s2.x) * a) * inv_d;
    float r5 = (x2.y + (acc2.y + s2.y) * a) * inv_d;
    float r6 = (x3.x + (acc3.x + s3.x) * a) * inv_d;
    float r7 = (x3.y + (acc3.y + s3.y) * a) * inv_d;
    if (last) {
        fx4* o = (fx4*)(out_f32 + base16);
        fx4 o0 = {r0, r1, r2, r3};
        fx4 o1 = {r4, r5, r6, r7};
        o[0] = o0;
        o[1] = o1;
    } else {
        ux4 ho;
        ho.x = pack2h(r0, r1); ho.y = pack2h(r2, r3);
        ho.z = pack2h(r4, r5); ho.w = pack2h(r6, r7);
        *(ux4*)(next16 + base16) = ho;
        uint2 q;
        q.x = pack4f8(r0, r1, r2, r3);
        q.y = pack4f8(r4, r5, r6, r7);
        *(uint2*)(next8 + (size_t)row * (DIM / 4) + loff8) = q;
    }
}

extern "C" void kernel_launch(void* const* d_in, const int* in_sizes, int n_in,
                              void* d_out, int out_size, void* d_ws, size_t ws_size,
                              hipStream_t stream) {
    const float* x     = (const float*)d_in[0];
    const float* alpha = (const float*)d_in[1];
    const float* beta  = (const float*)d_in[2];
    const float* sigma = (const float*)d_in[3];
    const float* eval_ = (const float*)d_in[4];
    const int* erow = (const int*)d_in[5];
    const int* ecol = (const int*)d_in[6];

    const int n   = in_sizes[0] / DIM;   // 16384
    const int nnz = in_sizes[4];         // 163840

    float* ws        = (float*)d_ws;
    float* consts    = ws;                            // 64 floats
    float* inv_denom = ws + 64;                       // n
    int*   rstart    = (int*)(inv_denom + n);         // n+1 (+pad)
    float* sup       = (float*)(rstart + n + 64);     // nnz
    unsigned short* xbh    = (unsigned short*)(sup + nnz);           // n*DIM fp16 (16 MB)
    unsigned short* bufB16 = xbh + (size_t)n * DIM;                  // n*DIM fp16 (16 MB)
    unsigned int*   xc8    = (unsigned int*)(bufB16 + (size_t)n * DIM); // n*256 uints (16 MB)
    unsigned int*   bufB8  = xc8 + (size_t)n * 256;                  // 8 MB
    unsigned int*   bufA8  = xc8;   // alias: xc8 is dead after fused1_kernel,
                                    // bufA8 first written by the k=0 iter launch
    unsigned short* bufA16 = (unsigned short*)d_out;                 // first 16 MB of d_out
    float* out_f32 = (float*)d_out;

    // merged consts + rowptr + rownorm
    prep_kernel<<<(n * 64) / 256, 256, 0, stream>>>(x, alpha, beta, sigma,
                                                    erow, nnz, consts, rstart,
                                                    xc8, xbh, n);
    // fused cosine-sim + sup + inv_denom + iteration 1 (writes B buffers)
    fused1_kernel<<<(n * 64) / 256, 256, 0, stream>>>(xc8, x, eval_, ecol, rstart,
                                                      consts, sup, inv_denom,
                                                      bufB16, bufB8, n);
    // iterations 2..10: k even reads B writes A; k odd reads A writes B;
    // k=8 (iteration 10) reads B and writes fp32 d_out.
    for (int k = 0; k < N_ITERS - 1; ++k) {
        const unsigned short* prev16 = (k & 1) ? bufA16 : bufB16;
        const unsigned int*   prev8  = (k & 1) ? bufA8  : bufB8;
        unsigned short* next16 = (k & 1) ? bufB16 : bufA16;
        unsigned int*   next8  = (k & 1) ? bufB8  : bufA8;
        int last = (k == N_ITERS - 2) ? 1 : 0;
        iter_kernel<<<(n * 64) / 256, 256, 0, stream>>>(prev16, prev8, next16, next8,
                                                        out_f32, last,
                                                        consts, inv_denom, sup, ecol,
                                                        rstart, xbh, n);
    }
}